// Round 4
// baseline (106.250 us; speedup 1.0000x reference)
//
#include <hip/hip_runtime.h>

// GAPooling: out[b,n,c] = mean_k x[b, idx[b,n,k], c]
// B=16, N=4096, K=32, C=64, fp32. idx int64-or-int32 (runtime-detected).
//
// R4: channel-planar LDS gather.
//   plane[c][n] layout -> gather of neighbor j = 4 x ds_read_b32, one shared
//   vaddr (j*4), plane picked by the 16-bit imm offset. Bank = j%32: full
//   32-bank spread, random j ~2-way aliasing (free per m136), vs R3's b128
//   4-bank-group layout (~8-way distinct-address serialization).
//   Grid = 16 b x 16 chunks x 2 point-halves = 512 blocks, 64 KiB LDS each
//   (2 blocks/CU). XCD swizzle: bid%8 = b%8 -> same-batch partial 16B output
//   writes of one 256B line merge in one XCD's L2.

#define BB 16
#define NN 4096
#define KK 32
#define CC 64
#define CCH 4                    // channels per chunk
#define NCHUNK (CC / CCH)        // 16
#define NHALF 2
#define PTS_PER_BLOCK (NN / NHALF)  // 2048
#define THREADS 512

// idx values < 4096: if idx is int64 (little-endian), all odd words are 0.
__device__ __forceinline__ int detect_is64(const int* __restrict__ w) {
    int v = w[2 * (threadIdx.x & 63) + 1];
    return (__ballot(v != 0) == 0ULL) ? 1 : 0;
}

__global__ __launch_bounds__(256)
void pack_idx_kernel(const int* __restrict__ idx32,
                     ushort* __restrict__ out16) {
    const int is64 = detect_is64(idx32);
    const int tid = blockIdx.x * blockDim.x + threadIdx.x;
    const int stride = gridDim.x * blockDim.x;
    const int M = BB * NN * KK;           // 2,097,152 indices
    if (is64) {
        const int4* __restrict__ in = (const int4*)idx32;   // 2 int64 per int4
        uint* __restrict__ o = (uint*)out16;                // 2 u16 per uint
        for (int i = tid; i < M / 2; i += stride) {
            int4 v = in[i];
            o[i] = (uint)(v.x & 0xFFFF) | ((uint)(v.z & 0xFFFF) << 16);
        }
    } else {
        const int4* __restrict__ in = (const int4*)idx32;   // 4 int32 per int4
        uint2* __restrict__ o = (uint2*)out16;
        for (int i = tid; i < M / 4; i += stride) {
            int4 v = in[i];
            o[i] = make_uint2((uint)(v.x & 0xFFFF) | ((uint)(v.y & 0xFFFF) << 16),
                              (uint)(v.z & 0xFFFF) | ((uint)(v.w & 0xFFFF) << 16));
        }
    }
}

__global__ __launch_bounds__(THREADS)
void gapool_planar_kernel(const float* __restrict__ x,
                          const ushort* __restrict__ idx16,
                          float* __restrict__ out) {
    __shared__ float plane[CCH][NN];      // 4 x 16 KiB = 64 KiB

    const int bid = blockIdx.x;           // g*16 + b, g = half*NCHUNK + chunk
    const int b = bid & 15;
    const int g = bid >> 4;               // 0..31
    const int chunk = g & (NCHUNK - 1);
    const int half = g >> 4;
    const int c0 = chunk * CCH;

    // ---- stage planes: lane r reads x[b][r][c0:c0+4] (16B), scatters to 4
    // planes at [c][r]; consecutive r -> bank r%32, conflict-free writes.
    const float* __restrict__ xb = x + ((size_t)b * NN) * CC + c0;
    for (int r = threadIdx.x; r < NN; r += THREADS) {
        const float4 v = *(const float4*)(xb + (size_t)r * CC);
        plane[0][r] = v.x;
        plane[1][r] = v.y;
        plane[2][r] = v.z;
        plane[3][r] = v.w;
    }
    __syncthreads();

    const int n0 = half * PTS_PER_BLOCK;
    const float s = 1.0f / KK;

    for (int p = threadIdx.x; p < PTS_PER_BLOCK; p += THREADS) {
        const int n = n0 + p;
        // 32 packed u16 indices: 64B per lane, coalesced uint4 loads.
        const uint4* __restrict__ ip =
            (const uint4*)(idx16 + ((size_t)b * NN + n) * KK);
        const uint4 u0 = ip[0], u1 = ip[1], u2 = ip[2], u3 = ip[3];
        const uint w[16] = {u0.x, u0.y, u0.z, u0.w, u1.x, u1.y, u1.z, u1.w,
                            u2.x, u2.y, u2.z, u2.w, u3.x, u3.y, u3.z, u3.w};

        float a0 = 0.f, a1 = 0.f, a2 = 0.f, a3 = 0.f;
#pragma unroll
        for (int i = 0; i < 16; ++i) {
            const int j0 = (int)(w[i] & 0xFFFFu);
            const int j1 = (int)(w[i] >> 16);
            a0 += plane[0][j0]; a1 += plane[1][j0];
            a2 += plane[2][j0]; a3 += plane[3][j0];
            a0 += plane[0][j1]; a1 += plane[1][j1];
            a2 += plane[2][j1]; a3 += plane[3][j1];
        }

        float4 r = make_float4(a0 * s, a1 * s, a2 * s, a3 * s);
        *(float4*)(out + ((size_t)b * NN + n) * CC + c0) = r;
    }
}

extern "C" void kernel_launch(void* const* d_in, const int* in_sizes, int n_in,
                              void* d_out, int out_size, void* d_ws, size_t ws_size,
                              hipStream_t stream) {
    const float* x     = (const float*)d_in[0];
    const int*   idx32 = (const int*)d_in[1];
    float*       out   = (float*)d_out;
    ushort*      idx16 = (ushort*)d_ws;     // 4 MiB of scratch

    pack_idx_kernel<<<1024, 256, 0, stream>>>(idx32, idx16);

    gapool_planar_kernel<<<NHALF * NCHUNK * BB, THREADS, 0, stream>>>(
        x, idx16, out);
}

// Round 5
// 92.712 us; speedup vs baseline: 1.1460x; 1.1460x over previous
//
#include <hip/hip_runtime.h>

// GAPooling: out[b,n,c] = mean_k x[b, idx[b,n,k], c]
// B=16, N=4096, K=32, C=64, fp32. idx int64-or-int32 (runtime-detected).
//
// R5: R3's b128 LDS-gather structure at 2 blocks/CU.
//   tile[n] = float4 of x[b][n][c0:c0+4] (64 KiB). Gather = 1 ds_read_b128
//   per neighbor (16 B/lane, BW-bound ~8cyc + random-group imbalance).
//   Grid = 16 b x 16 chunk x 2 half = 512 blocks -> 2 blocks/CU, 16 waves/CU;
//   sibling block's gather hides this block's staging + barrier.
//   __launch_bounds__(512,4): VGPR<=128 so 4 waves/SIMD actually fit.
//   XCD swizzle: bid%16 = b -> bid%8 = b%8: all chunks/halves of a batch on
//   one XCD; partial 16B output stores of a 256B line merge in that L2.

#define BB 16
#define NN 4096
#define KK 32
#define CC 64
#define CCH 4                       // channels per chunk
#define NCHUNK (CC / CCH)           // 16
#define NHALF 2
#define PTS_PER_BLOCK (NN / NHALF)  // 2048
#define THREADS 512

// idx values < 4096: if idx is int64 (little-endian), all odd words are 0.
__device__ __forceinline__ int detect_is64(const int* __restrict__ w) {
    int v = w[2 * (threadIdx.x & 63) + 1];
    return (__ballot(v != 0) == 0ULL) ? 1 : 0;
}

__global__ __launch_bounds__(256)
void pack_idx_kernel(const int* __restrict__ idx32,
                     ushort* __restrict__ out16) {
    const int is64 = detect_is64(idx32);
    const int tid = blockIdx.x * blockDim.x + threadIdx.x;
    const int stride = gridDim.x * blockDim.x;
    const int M = BB * NN * KK;           // 2,097,152 indices
    if (is64) {
        const int4* __restrict__ in = (const int4*)idx32;   // 2 int64 per int4
        uint* __restrict__ o = (uint*)out16;                // 2 u16 per uint
        for (int i = tid; i < M / 2; i += stride) {
            int4 v = in[i];
            o[i] = (uint)(v.x & 0xFFFF) | ((uint)(v.z & 0xFFFF) << 16);
        }
    } else {
        const int4* __restrict__ in = (const int4*)idx32;   // 4 int32 per int4
        uint2* __restrict__ o = (uint2*)out16;
        for (int i = tid; i < M / 4; i += stride) {
            int4 v = in[i];
            o[i] = make_uint2((uint)(v.x & 0xFFFF) | ((uint)(v.y & 0xFFFF) << 16),
                              (uint)(v.z & 0xFFFF) | ((uint)(v.w & 0xFFFF) << 16));
        }
    }
}

__global__ __launch_bounds__(THREADS, 4)
void gapool_lds_kernel(const float* __restrict__ x,
                       const ushort* __restrict__ idx16,
                       float* __restrict__ out) {
    __shared__ float4 tile[NN];           // 64 KiB: x[b][n][c0:c0+4]

    const int bid = blockIdx.x;           // (half*16 + chunk)*16 + b
    const int b = bid & 15;
    const int g = bid >> 4;
    const int chunk = g & (NCHUNK - 1);
    const int half = g >> 4;
    const int c0 = chunk * CCH;

    // ---- stage tile: lane r reads 16B of row r (64 KiB total per block) ----
    const float4* __restrict__ xb4 =
        (const float4*)(x + ((size_t)b * NN) * CC + c0);   // stride 16 float4s
    for (int r = threadIdx.x; r < NN; r += THREADS) {
        tile[r] = xb4[(size_t)r * (CC / 4)];
    }
    __syncthreads();

    const int n0 = half * PTS_PER_BLOCK;
    const float s = 1.0f / KK;

    for (int p = threadIdx.x; p < PTS_PER_BLOCK; p += THREADS) {
        const int n = n0 + p;
        // 32 packed u16 indices: 64B per lane, coalesced uint4 loads.
        const uint4* __restrict__ ip =
            (const uint4*)(idx16 + ((size_t)b * NN + n) * KK);
        const uint4 u0 = ip[0], u1 = ip[1], u2 = ip[2], u3 = ip[3];
        const uint w[16] = {u0.x, u0.y, u0.z, u0.w, u1.x, u1.y, u1.z, u1.w,
                            u2.x, u2.y, u2.z, u2.w, u3.x, u3.y, u3.z, u3.w};

        float4 acc0 = make_float4(0.f, 0.f, 0.f, 0.f);
        float4 acc1 = make_float4(0.f, 0.f, 0.f, 0.f);
#pragma unroll
        for (int i = 0; i < 16; ++i) {
            {
                const float4 v = tile[w[i] & 0xFFFFu];
                acc0.x += v.x; acc0.y += v.y; acc0.z += v.z; acc0.w += v.w;
            }
            {
                const float4 v = tile[w[i] >> 16];
                acc1.x += v.x; acc1.y += v.y; acc1.z += v.z; acc1.w += v.w;
            }
        }

        const float4 r = make_float4((acc0.x + acc1.x) * s,
                                     (acc0.y + acc1.y) * s,
                                     (acc0.z + acc1.z) * s,
                                     (acc0.w + acc1.w) * s);
        *(float4*)(out + ((size_t)b * NN + n) * CC + c0) = r;
    }
}

extern "C" void kernel_launch(void* const* d_in, const int* in_sizes, int n_in,
                              void* d_out, int out_size, void* d_ws, size_t ws_size,
                              hipStream_t stream) {
    const float* x     = (const float*)d_in[0];
    const int*   idx32 = (const int*)d_in[1];
    float*       out   = (float*)d_out;
    ushort*      idx16 = (ushort*)d_ws;     // 4 MiB of scratch

    pack_idx_kernel<<<1024, 256, 0, stream>>>(idx32, idx16);

    gapool_lds_kernel<<<BB * NCHUNK * NHALF, THREADS, 0, stream>>>(
        x, idx16, out);
}